// Round 1
// baseline (910.952 us; speedup 1.0000x reference)
//
#include <hip/hip_runtime.h>

// Problem: S=512, B=256, I=64, H=512, O=25.
// Key reduction: y depends only on batch element 255 (out[:, -1, :]), and the
// RNN recurrence is independent per batch row -> compute only row 255.
//
// Pipeline (3 kernels on `stream`):
//   rnn_pre : xi[t][h] = x[t,255,:] . W_ih[h,:] + b_ih[h] + b_hh[h]   (512x512)
//   rnn_seq : 512 sequential steps h = relu(xi_t + W_hh h_prev), distributed
//             over 16 blocks (32 rows each, W_hh rows register-resident).
//             Cross-block exchange via 64-bit (tag|value) relaxed agent atomics
//             in a double-buffered L3 slot; tag = s+1 (0xAA poison never
//             matches). Spin-poll IS the barrier (data-as-flag).
//   rnn_post: y[t] = h_t . W2^T + b2   (512x25)

#define S_ 512
#define B_ 256
#define I_ 64
#define H_ 512
#define O_ 25
#define G_ 16   // blocks in rnn_seq
#define R_ 32   // rows of W_hh per block (H_/G_)

__global__ __launch_bounds__(256) void rnn_pre(
    const float* __restrict__ x, const float* __restrict__ W_ih,
    const float* __restrict__ b_ih, const float* __restrict__ b_hh,
    float* __restrict__ xi) {
  const int t = blockIdx.x;
  const int tid = threadIdx.x;
  const int o = blockIdx.y * 256 + tid;
  __shared__ float xr[I_];
  if (tid < I_) xr[tid] = x[(t * B_ + (B_ - 1)) * I_ + tid];
  __syncthreads();
  float acc = b_ih[o] + b_hh[o];
  const float4* wp = (const float4*)(W_ih + o * I_);
#pragma unroll
  for (int j = 0; j < I_ / 4; ++j) {
    float4 w4 = wp[j];
    acc += w4.x * xr[4 * j] + w4.y * xr[4 * j + 1] + w4.z * xr[4 * j + 2] +
           w4.w * xr[4 * j + 3];
  }
  xi[t * H_ + o] = acc;
}

__global__ __launch_bounds__(256) void rnn_seq(
    const float* __restrict__ W_hh, const float* __restrict__ xi,
    float* __restrict__ hseq, unsigned long long* hg64) {
  const int tid = threadIdx.x;
  const int b = blockIdx.x;
  const int r = tid & 31;        // row within this block's 32 rows
  const int seg = tid >> 5;      // 0..7 : which 64-wide k-chunk
  const int row = b * R_ + r;    // global row of W_hh / h
  const int k0 = seg * 64;
  const int wave = tid >> 6;     // 0..3

  __shared__ float h_l[H_];      // h_{s-1}, full vector
  __shared__ float part[4 * R_]; // per-wave partial sums per row

  // W_hh rows resident in VGPRs: thread (r,seg) holds W_hh[row][k0..k0+63].
  float w[64];
  {
    const float4* wp = (const float4*)(W_hh + row * H_ + k0);
#pragma unroll
    for (int j = 0; j < 16; ++j) {
      float4 v = wp[j];
      w[4 * j] = v.x; w[4 * j + 1] = v.y; w[4 * j + 2] = v.z; w[4 * j + 3] = v.w;
    }
  }
  for (int n = tid; n < H_; n += 256) h_l[n] = 0.0f;  // h_{-1} = 0
  __syncthreads();

  for (int s = 0; s < S_; ++s) {
    // prefetch xi contribution early (L2-hot); consumed after the reduce
    float xiv = 0.0f;
    if (tid < R_) xiv = xi[s * H_ + b * R_ + r];

    // partial dot: 64 MACs per thread, h from LDS (2-addr broadcast = free)
    float acc = 0.0f;
    const float4* hp = (const float4*)(h_l + k0);
#pragma unroll
    for (int j = 0; j < 16; ++j) {
      float4 hv = hp[j];
      acc = fmaf(w[4 * j], hv.x, acc);
      acc = fmaf(w[4 * j + 1], hv.y, acc);
      acc = fmaf(w[4 * j + 2], hv.z, acc);
      acc = fmaf(w[4 * j + 3], hv.w, acc);
    }
    // fold seg pairs within each wave (lanes tid and tid^32 share r)
    acc += __shfl_xor(acc, 32, 64);
    if ((tid & 32) == 0) part[wave * R_ + r] = acc;
    __syncthreads();

    const int tag = s + 1;
    unsigned long long* buf = hg64 + (tag & 1) * H_;  // double buffer

    if (tid < R_) {
      float sum = part[r] + part[R_ + r] + part[2 * R_ + r] + part[3 * R_ + r] + xiv;
      float h = fmaxf(sum, 0.0f);
      hseq[s * H_ + b * R_ + r] = h;  // for rnn_post (plain store, flushed at kernel end)
      unsigned long long pk = ((unsigned long long)(unsigned)tag << 32) |
                              (unsigned long long)__float_as_uint(h);
      __hip_atomic_store(&buf[b * R_ + r], pk, __ATOMIC_RELAXED,
                         __HIP_MEMORY_SCOPE_AGENT);
    }

    // spin-poll reload of full h: each thread owns 2 elements.
    // Poison 0xAAAAAAAA tag is negative -> never matches tag in [1,512].
    for (int n = tid; n < H_; n += 256) {
      unsigned long long p;
      do {
        p = __hip_atomic_load(&buf[n], __ATOMIC_RELAXED, __HIP_MEMORY_SCOPE_AGENT);
      } while ((int)(unsigned)(p >> 32) != tag);
      h_l[n] = __uint_as_float((unsigned)p);
    }
    __syncthreads();
  }
}

__global__ __launch_bounds__(256) void rnn_post(
    const float* __restrict__ hseq, const float* __restrict__ W2,
    const float* __restrict__ b2, float* __restrict__ y) {
  const int t = blockIdx.x;
  const int tid = threadIdx.x;
  __shared__ float hl[H_];
  __shared__ float part[256];
  for (int n = tid; n < H_; n += 256) hl[n] = hseq[t * H_ + n];
  __syncthreads();
  const int o = tid >> 3;
  const int seg = tid & 7;
  float acc = 0.0f;
  if (o < O_) {  // guard: no OOB reads of W2 (25 rows)
    const float4* wp = (const float4*)(W2 + o * H_ + seg * 64);
    const float4* hp = (const float4*)(hl + seg * 64);
#pragma unroll
    for (int j = 0; j < 16; ++j) {
      float4 w4 = wp[j];
      float4 h4 = hp[j];
      acc += w4.x * h4.x + w4.y * h4.y + w4.z * h4.z + w4.w * h4.w;
    }
  }
  part[tid] = acc;
  __syncthreads();
  if (tid < O_) {
    float sum = 0.0f;
#pragma unroll
    for (int j = 0; j < 8; ++j) sum += part[tid * 8 + j];
    y[t * O_ + tid] = sum + b2[tid];
  }
}

extern "C" void kernel_launch(void* const* d_in, const int* in_sizes, int n_in,
                              void* d_out, int out_size, void* d_ws, size_t ws_size,
                              hipStream_t stream) {
  const float* x    = (const float*)d_in[0];
  const float* W_ih = (const float*)d_in[1];
  const float* W_hh = (const float*)d_in[2];
  const float* b_ih = (const float*)d_in[3];
  const float* b_hh = (const float*)d_in[4];
  const float* W2   = (const float*)d_in[5];
  const float* b2   = (const float*)d_in[6];
  float* y = (float*)d_out;

  // workspace layout (all within ~2.2 MB):
  float* xi   = (float*)d_ws;            // [512*512]
  float* hseq = xi + S_ * H_;            // [512*512]
  unsigned long long* hg64 = (unsigned long long*)(hseq + S_ * H_);  // [2*512]

  rnn_pre<<<dim3(S_, 2), 256, 0, stream>>>(x, W_ih, b_ih, b_hh, xi);
  rnn_seq<<<G_, 256, 0, stream>>>(W_hh, xi, hseq, hg64);
  rnn_post<<<S_, 256, 0, stream>>>(hseq, W2, b2, y);
}

// Round 2
// 819.635 us; speedup vs baseline: 1.1114x; 1.1114x over previous
//
#include <hip/hip_runtime.h>

// Problem: S=512, B=256, I=64, H=512, O=25.
// y depends only on batch row 255 (out[:, -1, :]) and the recurrence is
// per-row independent -> compute only row 255.
//
//   rnn_pre : xi[t][h] = x[t,255,:] . W_ih[h,:] + b_ih[h] + b_hh[h]; also
//             re-inits the exchange buffers (sign=1 = not-ready).
//   rnn_seq : 512 sequential steps h = relu(xi_t + W_hh h_prev) on 16 blocks
//             (32 rows each, W_hh register-resident). Cross-block exchange:
//             32-bit values with generation encoded in the SIGN BIT (relu =>
//             h >= 0), double-buffered by s&1, generation = (s>>1)&1.
//             Progress invariant bounds inter-block skew to <2 steps, which
//             this encoding exactly disambiguates. Relaxed agent atomics;
//             data-as-flag (no fences).
//   rnn_post: y[t] = h_t . W2^T + b2   (512x25)

#define S_ 512
#define B_ 256
#define I_ 64
#define H_ 512
#define O_ 25
#define G_ 16   // blocks in rnn_seq
#define R_ 32   // rows per block (H_/G_)

__global__ __launch_bounds__(256) void rnn_pre(
    const float* __restrict__ x, const float* __restrict__ W_ih,
    const float* __restrict__ b_ih, const float* __restrict__ b_hh,
    float* __restrict__ xi, unsigned* __restrict__ hg) {
  const int t = blockIdx.x;
  const int tid = threadIdx.x;
  const int o = blockIdx.y * 256 + tid;
  if (t == 0 && blockIdx.y == 0) {
    // init both exchange buffers to sign=1 (not-ready for generation 0);
    // done every launch so no reliance on workspace poison or prior state.
    hg[tid] = 0x80000000u;
    hg[tid + 256] = 0x80000000u;
    hg[tid + 512] = 0x80000000u;
    hg[tid + 768] = 0x80000000u;
  }
  __shared__ float xr[I_];
  if (tid < I_) xr[tid] = x[(t * B_ + (B_ - 1)) * I_ + tid];
  __syncthreads();
  float acc = b_ih[o] + b_hh[o];
  const float4* wp = (const float4*)(W_ih + o * I_);
#pragma unroll
  for (int j = 0; j < I_ / 4; ++j) {
    float4 w4 = wp[j];
    acc += w4.x * xr[4 * j] + w4.y * xr[4 * j + 1] + w4.z * xr[4 * j + 2] +
           w4.w * xr[4 * j + 3];
  }
  xi[t * H_ + o] = acc;
}

__global__ __launch_bounds__(256) void rnn_seq(
    const float* __restrict__ W_hh, const float* __restrict__ xi,
    float* __restrict__ hseq, unsigned* __restrict__ hg) {
  const int tid = threadIdx.x;
  const int b = blockIdx.x;
  const int r = tid & 31;        // row within block's 32 rows
  const int seg = tid >> 5;      // 0..7 : 64-wide k-chunk
  const int row = b * R_ + r;
  const int k0 = seg * 64;
  const int wave = tid >> 6;
  const int own_lo = b * R_;
  const int own_hi = b * R_ + R_;

  __shared__ float h_l[H_];
  __shared__ float part[4 * R_];

  // W_hh register-resident: thread (r,seg) holds W_hh[row][k0..k0+63].
  float w[64];
  {
    const float4* wp = (const float4*)(W_hh + row * H_ + k0);
#pragma unroll
    for (int j = 0; j < 16; ++j) {
      float4 v = wp[j];
      w[4 * j] = v.x; w[4 * j + 1] = v.y; w[4 * j + 2] = v.z; w[4 * j + 3] = v.w;
    }
  }
  for (int n = tid; n < H_; n += 256) h_l[n] = 0.0f;  // h_{-1} = 0

  // xi for step 0, prefetched; later steps prefetched during poll phase.
  float xiv = (tid < R_) ? xi[own_lo + tid] : 0.0f;
  __syncthreads();

  const int n0 = tid, n1 = tid + 256;
  const bool own0 = (n0 >= own_lo && n0 < own_hi);
  const bool own1 = (n1 >= own_lo && n1 < own_hi);

  for (int s = 0; s < S_; ++s) {
    // partial dot, 4 independent accumulator chains
    float a0 = 0.f, a1 = 0.f, a2 = 0.f, a3 = 0.f;
    const float4* hp = (const float4*)(h_l + k0);
#pragma unroll
    for (int j = 0; j < 16; ++j) {
      float4 hv = hp[j];
      a0 = fmaf(w[4 * j + 0], hv.x, a0);
      a1 = fmaf(w[4 * j + 1], hv.y, a1);
      a2 = fmaf(w[4 * j + 2], hv.z, a2);
      a3 = fmaf(w[4 * j + 3], hv.w, a3);
    }
    float acc = (a0 + a1) + (a2 + a3);
    acc += __shfl_xor(acc, 32, 64);          // fold seg pairs within wave
    if ((tid & 32) == 0) part[wave * R_ + r] = acc;
    __syncthreads();

    const unsigned phase = (unsigned)((s >> 1) & 1);
    unsigned* buf = hg + (s & 1) * H_;

    if (tid < R_) {
      float sum = part[tid] + part[R_ + tid] + part[2 * R_ + tid] +
                  part[3 * R_ + tid] + xiv;
      float h = fmaxf(sum, 0.0f);
      h_l[own_lo + tid] = h;                  // own rows: LDS-direct, no RTT
      hseq[s * H_ + own_lo + tid] = h;        // for rnn_post
      __hip_atomic_store(&buf[own_lo + tid],
                         __float_as_uint(h) | (phase << 31),
                         __ATOMIC_RELAXED, __HIP_MEMORY_SCOPE_AGENT);
    }

    if (s == S_ - 1) break;                   // no poll needed after last step

    // prefetch next step's xi (hidden under the poll RTT)
    if (tid < R_) xiv = xi[(s + 1) * H_ + own_lo + tid];

    // poll remote entries, both in flight concurrently
    bool need0 = !own0, need1 = !own1;
    unsigned p0, p1;
    while (need0 | need1) {
      if (need0)
        p0 = __hip_atomic_load(&buf[n0], __ATOMIC_RELAXED, __HIP_MEMORY_SCOPE_AGENT);
      if (need1)
        p1 = __hip_atomic_load(&buf[n1], __ATOMIC_RELAXED, __HIP_MEMORY_SCOPE_AGENT);
      if (need0 && (p0 >> 31) == phase) {
        h_l[n0] = __uint_as_float(p0 & 0x7fffffffu);
        need0 = false;
      }
      if (need1 && (p1 >> 31) == phase) {
        h_l[n1] = __uint_as_float(p1 & 0x7fffffffu);
        need1 = false;
      }
    }
    __syncthreads();
  }
}

__global__ __launch_bounds__(256) void rnn_post(
    const float* __restrict__ hseq, const float* __restrict__ W2,
    const float* __restrict__ b2, float* __restrict__ y) {
  const int t = blockIdx.x;
  const int tid = threadIdx.x;
  __shared__ float hl[H_];
  __shared__ float part[256];
  for (int n = tid; n < H_; n += 256) hl[n] = hseq[t * H_ + n];
  __syncthreads();
  const int o = tid >> 3;
  const int seg = tid & 7;
  float acc = 0.0f;
  if (o < O_) {
    const float4* wp = (const float4*)(W2 + o * H_ + seg * 64);
    const float4* hp = (const float4*)(hl + seg * 64);
#pragma unroll
    for (int j = 0; j < 16; ++j) {
      float4 w4 = wp[j];
      float4 h4 = hp[j];
      acc += w4.x * h4.x + w4.y * h4.y + w4.z * h4.z + w4.w * h4.w;
    }
  }
  part[tid] = acc;
  __syncthreads();
  if (tid < O_) {
    float sum = 0.0f;
#pragma unroll
    for (int j = 0; j < 8; ++j) sum += part[tid * 8 + j];
    y[t * O_ + tid] = sum + b2[tid];
  }
}

extern "C" void kernel_launch(void* const* d_in, const int* in_sizes, int n_in,
                              void* d_out, int out_size, void* d_ws, size_t ws_size,
                              hipStream_t stream) {
  const float* x    = (const float*)d_in[0];
  const float* W_ih = (const float*)d_in[1];
  const float* W_hh = (const float*)d_in[2];
  const float* b_ih = (const float*)d_in[3];
  const float* b_hh = (const float*)d_in[4];
  const float* W2   = (const float*)d_in[5];
  const float* b2   = (const float*)d_in[6];
  float* y = (float*)d_out;

  float* xi   = (float*)d_ws;            // [512*512]
  float* hseq = xi + S_ * H_;            // [512*512]
  unsigned* hg = (unsigned*)(hseq + S_ * H_);  // [2*512] sign-tagged exchange

  rnn_pre<<<dim3(S_, 2), 256, 0, stream>>>(x, W_ih, b_ih, b_hh, xi, hg);
  rnn_seq<<<G_, 256, 0, stream>>>(W_hh, xi, hseq, hg);
  rnn_post<<<S_, 256, 0, stream>>>(hseq, W2, b2, y);
}